// Round 1
// baseline (42.866 us; speedup 1.0000x reference)
//
#include <hip/hip_runtime.h>

namespace {

constexpr int TPB = 64;

// R = I + s*H + (1-c)*H*H, H = hat(axis)  (matches reference exactly, no
// unit-axis assumption folded in).
__device__ __forceinline__ void joint_rot(float a, float x, float y, float z, float* R) {
  float s = __sinf(a);
  float c = __cosf(a);
  float t = 1.0f - c;
  R[0] = 1.0f - t * (y * y + z * z);
  R[1] = t * (x * y) - s * z;
  R[2] = t * (x * z) + s * y;
  R[3] = t * (x * y) + s * z;
  R[4] = 1.0f - t * (x * x + z * z);
  R[5] = t * (y * z) - s * x;
  R[6] = t * (x * z) - s * y;
  R[7] = t * (y * z) + s * x;
  R[8] = 1.0f - t * (x * x + y * y);
}

__global__ __launch_bounds__(TPB) void fk_kernel(
    const float* __restrict__ angles,
    const float* __restrict__ axes,
    const float* __restrict__ min_rad,
    const float* __restrict__ max_rad,
    const float* __restrict__ trans,
    float* __restrict__ out) {
  // Staging buffer: reused first for angles (64*23 f32 = 5.75 KB fits), then
  // for outputs (64*63 f32 = 15.75 KB).
  __shared__ float lds[TPB * 63];

  const int tid = threadIdx.x;
  const long long base = (long long)blockIdx.x * TPB;

  // ---- coalesced stage of this block's angles into LDS (368 float4) ----
  {
    const float4* __restrict__ src = reinterpret_cast<const float4*>(angles + base * 23);
    float4* dst = reinterpret_cast<float4*>(lds);
#pragma unroll
    for (int k = 0; k < 6; ++k) {
      int idx = tid + k * TPB;
      if (idx < (TPB * 23) / 4) dst[idx] = src[idx];
    }
  }
  __syncthreads();

  // ---- per-thread angles to registers (stride 23: 2-way bank alias, free) ----
  float ang[23];
#pragma unroll
  for (int j = 0; j < 23; ++j) ang[j] = lds[tid * 23 + j];
  __syncthreads();  // LDS now free for output staging

  // Static tree description (fully constant-folded after unroll).
  constexpr int PAR[28] = {-1, 0, 1, 2, 3, 4, 0, 6, 7, 8, 9, 0, 11, 12, 13, 14,
                           0, 16, 17, 18, 19, 20, 0, 22, 23, 24, 25, 26};
  constexpr int JNT[28] = {0, 1, 2, 3, 4, -1, 5, 6, 7, 8, -1, 9, 10, 11, 12, -1,
                           13, 14, 15, 16, 17, -1, 18, 19, 20, 21, 22, -1};
  // node -> output keypoint row (position in KEYPOINTS), -1 if not emitted
  constexpr int SLOT[28] = {0, 5, -1, 6, 7, 8, 9, -1, 10, 11, 12, 13, -1, 14, 15, 16,
                            -1, 17, -1, 18, 19, 20, 1, -1, -1, 2, 3, 4};

  float* o = lds + tid * 63;  // stride 63: 2-way bank alias, free

  // ---- node 0 (root) ----
  float Rw0[9];
  {
    float a = fminf(fmaxf(ang[0], min_rad[0]), max_rad[0]);
    joint_rot(a, axes[0], axes[1], axes[2], Rw0);
  }
  float tw0[3] = {trans[0], trans[1], trans[2]};
  o[0] = tw0[0];
  o[1] = tw0[1];
  o[2] = tw0[2];

  // ---- walk chains; PARENTS[n] is always 0 or n-1 ----
  float Rc[9], tc[3];
#pragma unroll
  for (int n = 1; n < 28; ++n) {
    if (PAR[n] == 0) {
#pragma unroll
      for (int k = 0; k < 9; ++k) Rc[k] = Rw0[k];
      tc[0] = tw0[0];
      tc[1] = tw0[1];
      tc[2] = tw0[2];
    }
    const float tx = trans[3 * n + 0];
    const float ty = trans[3 * n + 1];
    const float tz = trans[3 * n + 2];
    float nt0 = tc[0] + Rc[0] * tx + Rc[1] * ty + Rc[2] * tz;
    float nt1 = tc[1] + Rc[3] * tx + Rc[4] * ty + Rc[5] * tz;
    float nt2 = tc[2] + Rc[6] * tx + Rc[7] * ty + Rc[8] * tz;
    if (JNT[n] >= 0) {
      const int j = JNT[n];
      float a = fminf(fmaxf(ang[j], min_rad[j]), max_rad[j]);
      float Rj[9];
      joint_rot(a, axes[3 * j + 0], axes[3 * j + 1], axes[3 * j + 2], Rj);
      float Rt[9];
#pragma unroll
      for (int r = 0; r < 3; ++r) {
#pragma unroll
        for (int c2 = 0; c2 < 3; ++c2) {
          Rt[3 * r + c2] = Rc[3 * r + 0] * Rj[0 + c2] +
                           Rc[3 * r + 1] * Rj[3 + c2] +
                           Rc[3 * r + 2] * Rj[6 + c2];
        }
      }
#pragma unroll
      for (int k = 0; k < 9; ++k) Rc[k] = Rt[k];
    }
    tc[0] = nt0;
    tc[1] = nt1;
    tc[2] = nt2;
    if (SLOT[n] >= 0) {
      o[SLOT[n] * 3 + 0] = nt0;
      o[SLOT[n] * 3 + 1] = nt1;
      o[SLOT[n] * 3 + 2] = nt2;
    }
  }
  __syncthreads();

  // ---- coalesced store of staged outputs (1008 float4) ----
  {
    float4* dst = reinterpret_cast<float4*>(out + base * 63);
    const float4* src = reinterpret_cast<const float4*>(lds);
#pragma unroll
    for (int k = 0; k < 16; ++k) {
      int idx = tid + k * TPB;
      if (idx < (TPB * 63) / 4) dst[idx] = src[idx];
    }
  }
}

}  // namespace

extern "C" void kernel_launch(void* const* d_in, const int* in_sizes, int n_in,
                              void* d_out, int out_size, void* d_ws, size_t ws_size,
                              hipStream_t stream) {
  const float* angles = (const float*)d_in[0];
  const float* axes = (const float*)d_in[1];
  const float* mn = (const float*)d_in[2];
  const float* mx = (const float*)d_in[3];
  const float* tr = (const float*)d_in[4];
  float* out = (float*)d_out;

  const int Bn = in_sizes[0] / 23;      // 524288
  const int nblocks = Bn / TPB;         // 8192 (B divisible by 64)
  fk_kernel<<<nblocks, TPB, 0, stream>>>(angles, axes, mn, mx, tr, out);
}

// Round 2
// 33.309 us; speedup vs baseline: 1.2869x; 1.2869x over previous
//
#include <hip/hip_runtime.h>

namespace {

constexpr int TPB = 64;

__device__ __forceinline__ float clampf(float x, float lo, float hi) {
  return fminf(fmaxf(x, lo), hi);
}

// All constants (axes, joint limits, translations) are static in the
// reference module, so they are hard-coded here and fully constant-folded.
// Tree structure: 5 chains hanging off node 0 (axis-X root rotation).
// 22 of 23 joint axes are elementary; consecutive X-rotations compose as
// cumulative angle sums, so each finger is: sincos of running sums + a few
// FMAs in the post-knuckle frame, then one world transform per keypoint.

__global__ __launch_bounds__(TPB, 4) void fk_kernel(
    const float* __restrict__ angles,
    float* __restrict__ out) {
  // 8064 B: reused for angle staging (1472 f32) then two 32-element
  // output staging phases (32*63 = 2016 f32).
  __shared__ float lds[32 * 63];

  const int tid = threadIdx.x;
  const long long base = (long long)blockIdx.x * TPB;

  // ---- coalesced stage of this block's angles (368 float4) ----
  {
    const float4* __restrict__ src = reinterpret_cast<const float4*>(angles + base * 23);
    float4* dst = reinterpret_cast<float4*>(lds);
#pragma unroll
    for (int k = 0; k < 6; ++k) {
      int idx = tid + k * TPB;
      if (idx < (TPB * 23) / 4) dst[idx] = src[idx];
    }
  }
  __syncthreads();

  float a[23];
#pragma unroll
  for (int j = 0; j < 23; ++j) a[j] = lds[tid * 23 + j];
  __syncthreads();  // all reads done; LDS free for output staging

  // ---- clamp to joint limits (hard-coded) ----
  a[0] = clampf(a[0], -0.689f, 0.489f);
  a[1] = clampf(a[1], -0.349f, 0.349f);
  a[2] = clampf(a[2], 0.0f, 1.571f);
  a[3] = clampf(a[3], 0.0f, 1.571f);
  a[4] = clampf(a[4], 0.0f, 1.571f);
  a[5] = clampf(a[5], -0.349f, 0.349f);
  a[6] = clampf(a[6], 0.0f, 1.571f);
  a[7] = clampf(a[7], 0.0f, 1.571f);
  a[8] = clampf(a[8], 0.0f, 1.571f);
  a[9] = clampf(a[9], -0.349f, 0.349f);
  a[10] = clampf(a[10], 0.0f, 1.571f);
  a[11] = clampf(a[11], 0.0f, 1.571f);
  a[12] = clampf(a[12], 0.0f, 1.571f);
  a[13] = clampf(a[13], 0.0f, 0.785f);
  a[14] = clampf(a[14], -0.349f, 0.349f);
  a[15] = clampf(a[15], 0.0f, 1.571f);
  a[16] = clampf(a[16], 0.0f, 1.571f);
  a[17] = clampf(a[17], 0.0f, 1.571f);
  a[18] = clampf(a[18], -1.047f, 1.047f);
  a[19] = clampf(a[19], 0.0f, 1.222f);
  a[20] = clampf(a[20], -0.209f, 0.209f);
  a[21] = clampf(a[21], -0.524f, 0.524f);
  a[22] = clampf(a[22], -1.571f, 0.0f);

  float o[63];  // 21 keypoints x 3, compile-time-indexed only

  const float s0 = __sinf(a[0]);
  const float c0 = __cosf(a[0]);

  // row 0: root at origin
  o[0] = 0.0f; o[1] = 0.0f; o[2] = 0.0f;

// ---- finger chains A/B/C: t=(TX,0,TZ), Ry(knuckle), then 3x Rx with
// z-links 0.045/0.025/0.026. Rows RB..RB+3. All indices literal. ----
#define FINGER(TX, TZ, AY, AX1, AX2, AX3, RB)                                   \
  {                                                                             \
    const float sY = __sinf(AY), cY = __cosf(AY);                               \
    const float g1 = (AX1);                                                     \
    const float g2 = g1 + (AX2);                                                \
    const float g3 = g2 + (AX3);                                                \
    const float s1 = __sinf(g1), c1 = __cosf(g1);                               \
    const float s2 = __sinf(g2), c2 = __cosf(g2);                               \
    const float s3 = __sinf(g3), c3 = __cosf(g3);                               \
    const float t1x = (TX), t1y = -s0 * (TZ), t1z = c0 * (TZ);                  \
    o[3 * (RB) + 0] = t1x; o[3 * (RB) + 1] = t1y; o[3 * (RB) + 2] = t1z;        \
    const float vx = sY, vy = -s0 * cY, vz = c0 * cY; /* frame col2 */          \
    /* frame col1 = (0, c0, s0) */                                              \
    const float q3y = -0.045f * s1, q3z = 0.045f * c1;                          \
    const float q4y = q3y - 0.025f * s2, q4z = q3z + 0.025f * c2;               \
    const float q5y = q4y - 0.026f * s3, q5z = q4z + 0.026f * c3;               \
    o[3 * ((RB) + 1) + 0] = t1x + q3z * vx;                                     \
    o[3 * ((RB) + 1) + 1] = t1y + q3y * c0 + q3z * vy;                          \
    o[3 * ((RB) + 1) + 2] = t1z + q3y * s0 + q3z * vz;                          \
    o[3 * ((RB) + 2) + 0] = t1x + q4z * vx;                                     \
    o[3 * ((RB) + 2) + 1] = t1y + q4y * c0 + q4z * vy;                          \
    o[3 * ((RB) + 2) + 2] = t1z + q4y * s0 + q4z * vz;                          \
    o[3 * ((RB) + 3) + 0] = t1x + q5z * vx;                                     \
    o[3 * ((RB) + 3) + 1] = t1y + q5y * c0 + q5z * vy;                          \
    o[3 * ((RB) + 3) + 2] = t1z + q5y * s0 + q5z * vz;                          \
  }

  FINGER(0.033f, 0.095f, a[1], a[2], a[3], a[4], 5)     // chain A: rows 5-8
  FINGER(0.011f, 0.099f, a[5], a[6], a[7], a[8], 9)     // chain B: rows 9-12
  FINGER(-0.011f, 0.095f, a[9], a[10], a[11], a[12], 13) // chain C: rows 13-16
#undef FINGER

  // ---- chain D (little finger w/ metacarpal): Rodrigues about
  // w=(0.571,0,0.821), then Ry, then 3x Rx. Rows 17-20. ----
  {
    const float wx = 0.571f, wz = 0.821f;
    const float s13 = __sinf(a[13]), c13 = __cosf(a[13]);
    const float t13 = 1.0f - c13;
    const float g00 = 1.0f - t13 * (wz * wz), g10 = s13 * wz, g20 = t13 * (wx * wz);
    const float g01 = -s13 * wz, g11 = 1.0f - t13 * (wx * wx + wz * wz), g21 = s13 * wx;
    const float g02 = t13 * (wx * wz), g12 = -s13 * wx, g22 = 1.0f - t13 * (wx * wx);
    // t17 = R0*(-0.017,0,0.044) + R0*G*(-0.017,0,0.044)
    const float gdx = -0.017f * g00 + 0.044f * g02;
    const float gdy = -0.017f * g10 + 0.044f * g12;
    const float gdz = -0.017f * g20 + 0.044f * g22;
    const float t17x = -0.017f + gdx;
    const float t17y = -0.044f * s0 + (c0 * gdy - s0 * gdz);
    const float t17z = 0.044f * c0 + (s0 * gdy + c0 * gdz);
    o[51] = t17x; o[52] = t17y; o[53] = t17z;  // row 17
    const float s14 = __sinf(a[14]), c14 = __cosf(a[14]);
    // u = R17 col1 = Rx(a0)*Gcol1 ; v = R17 col2 = Rx(a0)*(s14*Gcol0 + c14*Gcol2)
    const float ux = g01, uy = c0 * g11 - s0 * g21, uz = s0 * g11 + c0 * g21;
    const float mx = s14 * g00 + c14 * g02;
    const float my = s14 * g10 + c14 * g12;
    const float mz = s14 * g20 + c14 * g22;
    const float vx = mx, vy = c0 * my - s0 * mz, vz = s0 * my + c0 * mz;
    const float g1 = a[15], g2 = g1 + a[16], g3 = g2 + a[17];
    const float s1 = __sinf(g1), c1 = __cosf(g1);
    const float s2 = __sinf(g2), c2 = __cosf(g2);
    const float s3 = __sinf(g3), c3 = __cosf(g3);
    const float q3y = -0.045f * s1, q3z = 0.045f * c1;
    const float q4y = q3y - 0.025f * s2, q4z = q3z + 0.025f * c2;
    const float q5y = q4y - 0.026f * s3, q5z = q4z + 0.026f * c3;
    o[54] = t17x + q3y * ux + q3z * vx;  // row 18
    o[55] = t17y + q3y * uy + q3z * vy;
    o[56] = t17z + q3y * uz + q3z * vz;
    o[57] = t17x + q4y * ux + q4z * vx;  // row 19
    o[58] = t17y + q4y * uy + q4z * vy;
    o[59] = t17z + q4y * uz + q4z * vz;
    o[60] = t17x + q5y * ux + q5z * vx;  // row 20
    o[61] = t17y + q5y * uy + q5z * vy;
    o[62] = t17z + q5y * uz + q5z * vz;
  }

  // ---- chain E (thumb): Rz(-a18), Rx(a19), Rx(a20), Ry(a21), Ry(a22).
  // Rows 1-4. ----
  {
    const float s18 = __sinf(a[18]), c18 = __cosf(a[18]);
    const float t22x = 0.034f;
    const float t22y = -0.009f * c0 - 0.029f * s0;
    const float t22z = -0.009f * s0 + 0.029f * c0;
    o[3] = t22x; o[4] = t22y; o[5] = t22z;  // row 1 (node 22)
    const float s19 = __sinf(a[19]), c19 = __cosf(a[19]);
    const float sg = a[19] + a[20];
    const float ss = __sinf(sg), cs = __cosf(sg);
    const float s21 = __sinf(a[21]), c21 = __cosf(a[21]);
    const float ta = a[21] + a[22];
    const float st = __sinf(ta), ct = __cosf(ta);
    // local (R22-frame) positions
    const float qAy = -0.038f * s19, qAz = 0.038f * c19;               // node 25
    const float q6x = 0.032f * s21;
    const float q6y = qAy - 0.032f * c21 * ss;
    const float q6z = qAz + 0.032f * c21 * cs;                         // node 26
    const float q7x = q6x + 0.0275f * st;
    const float q7y = q6y - 0.0275f * ct * ss;
    const float q7z = q6z + 0.0275f * ct * cs;                         // node 27
    // R22 cols: c0l0=(c18,-c0*s18,-s0*s18) col1=(s18,c0*c18,s0*c18) col2=(0,-s0,c0)
    const float m10 = c0 * s18, m11 = c0 * c18, m20 = s0 * s18, m21 = s0 * c18;
    o[6] = t22x + qAy * s18;                    // row 2 (node 25)
    o[7] = t22y + qAy * m11 - qAz * s0;
    o[8] = t22z + qAy * m21 + qAz * c0;
    o[9] = t22x + q6x * c18 + q6y * s18;        // row 3 (node 26)
    o[10] = t22y - q6x * m10 + q6y * m11 - q6z * s0;
    o[11] = t22z - q6x * m20 + q6y * m21 + q6z * c0;
    o[12] = t22x + q7x * c18 + q7y * s18;       // row 4 (node 27)
    o[13] = t22y - q7x * m10 + q7y * m11 - q7z * s0;
    o[14] = t22z - q7x * m20 + q7y * m21 + q7z * c0;
  }

  // ---- two-phase output staging: 32 elements' full 63-float rows at a
  // time -> contiguous float4 global stores. ----
#pragma unroll
  for (int p = 0; p < 2; ++p) {
    if ((tid >> 5) == p) {
      float* dst = lds + (tid & 31) * 63;  // stride 63: banks distinct mod 32
#pragma unroll
      for (int k = 0; k < 63; ++k) dst[k] = o[k];
    }
    __syncthreads();
    const float4* lsrc = reinterpret_cast<const float4*>(lds);
    float4* gdst = reinterpret_cast<float4*>(out + (base + 32 * p) * 63);
#pragma unroll
    for (int it = 0; it < 8; ++it) {
      int idx = tid + it * TPB;
      if (idx < (32 * 63) / 4) gdst[idx] = lsrc[idx];
    }
    __syncthreads();  // phase-0 reads done before phase-1 overwrites
  }
}

}  // namespace

extern "C" void kernel_launch(void* const* d_in, const int* in_sizes, int n_in,
                              void* d_out, int out_size, void* d_ws, size_t ws_size,
                              hipStream_t stream) {
  const float* angles = (const float*)d_in[0];
  float* out = (float*)d_out;
  const int Bn = in_sizes[0] / 23;   // 524288
  const int nblocks = Bn / TPB;      // 8192
  fk_kernel<<<nblocks, TPB, 0, stream>>>(angles, out);
}

// Round 3
// 33.159 us; speedup vs baseline: 1.2927x; 1.0045x over previous
//
#include <hip/hip_runtime.h>

namespace {

constexpr int TPB = 64;

__device__ __forceinline__ float clampf(float x, float lo, float hi) {
  return fminf(fmaxf(x, lo), hi);
}

// All constants (axes, joint limits, translations) are static in the
// reference module and hard-coded/folded. 5 chains hang off node 0 (X-axis
// root rotation); consecutive X-rotations compose as cumulative angle sums.
//
// Register diet vs R2: angles are NOT held in a register array — they are
// read lazily per chain from the LDS staging buffer (stride-23 b32, 2-way
// bank alias = free on CDNA4), clamped at read. This drops ~20 live VGPRs
// so launch_bounds(64,5) (cap 102) holds without spill -> 20 waves/CU
// (LDS cap 163840/8064 = 20 blocks).

__global__ __launch_bounds__(TPB, 5) void fk_kernel(
    const float* __restrict__ angles,
    float* __restrict__ out) {
  // 8064 B: angle staging (1472 f32) first, then reused for two 32-element
  // output staging phases (32*63 = 2016 f32).
  __shared__ float lds[32 * 63];

  const int tid = threadIdx.x;
  const long long base = (long long)blockIdx.x * TPB;

  // ---- coalesced stage of this block's angles (368 float4) ----
  {
    const float4* __restrict__ src = reinterpret_cast<const float4*>(angles + base * 23);
    float4* dst = reinterpret_cast<float4*>(lds);
#pragma unroll
    for (int k = 0; k < 6; ++k) {
      int idx = tid + k * TPB;
      if (idx < (TPB * 23) / 4) dst[idx] = src[idx];
    }
  }
  __syncthreads();

  const float* al = lds + tid * 23;  // this thread's angles (lazy reads)

  float o[63];  // 21 keypoints x 3, compile-time-indexed only

  const float a0 = clampf(al[0], -0.689f, 0.489f);
  const float s0 = __sinf(a0);
  const float c0 = __cosf(a0);

  // row 0: root at origin
  o[0] = 0.0f; o[1] = 0.0f; o[2] = 0.0f;

// ---- finger chains A/B/C: t=(TX,0,TZ), Ry(knuckle), then 3x Rx with
// z-links 0.045/0.025/0.026. Rows RB..RB+3. All indices literal. ----
#define FINGER(TX, TZ, JY, LOY, RB)                                             \
  {                                                                             \
    const float aY = clampf(al[(JY)], (LOY), -(LOY));                           \
    const float sY = __sinf(aY), cY = __cosf(aY);                               \
    const float g1 = clampf(al[(JY) + 1], 0.0f, 1.571f);                        \
    const float g2 = g1 + clampf(al[(JY) + 2], 0.0f, 1.571f);                   \
    const float g3 = g2 + clampf(al[(JY) + 3], 0.0f, 1.571f);                   \
    const float s1 = __sinf(g1), c1 = __cosf(g1);                               \
    const float s2 = __sinf(g2), c2 = __cosf(g2);                               \
    const float s3 = __sinf(g3), c3 = __cosf(g3);                               \
    const float t1x = (TX), t1y = -s0 * (TZ), t1z = c0 * (TZ);                  \
    o[3 * (RB) + 0] = t1x; o[3 * (RB) + 1] = t1y; o[3 * (RB) + 2] = t1z;        \
    const float vx = sY, vy = -s0 * cY, vz = c0 * cY; /* frame col2 */          \
    /* frame col1 = (0, c0, s0) */                                              \
    const float q3y = -0.045f * s1, q3z = 0.045f * c1;                          \
    const float q4y = q3y - 0.025f * s2, q4z = q3z + 0.025f * c2;               \
    const float q5y = q4y - 0.026f * s3, q5z = q4z + 0.026f * c3;               \
    o[3 * ((RB) + 1) + 0] = t1x + q3z * vx;                                     \
    o[3 * ((RB) + 1) + 1] = t1y + q3y * c0 + q3z * vy;                          \
    o[3 * ((RB) + 1) + 2] = t1z + q3y * s0 + q3z * vz;                          \
    o[3 * ((RB) + 2) + 0] = t1x + q4z * vx;                                     \
    o[3 * ((RB) + 2) + 1] = t1y + q4y * c0 + q4z * vy;                          \
    o[3 * ((RB) + 2) + 2] = t1z + q4y * s0 + q4z * vz;                          \
    o[3 * ((RB) + 3) + 0] = t1x + q5z * vx;                                     \
    o[3 * ((RB) + 3) + 1] = t1y + q5y * c0 + q5z * vy;                          \
    o[3 * ((RB) + 3) + 2] = t1z + q5y * s0 + q5z * vz;                          \
  }

  FINGER(0.033f, 0.095f, 1, -0.349f, 5)    // chain A: rows 5-8,  joints 1-4
  FINGER(0.011f, 0.099f, 5, -0.349f, 9)    // chain B: rows 9-12, joints 5-8
  FINGER(-0.011f, 0.095f, 9, -0.349f, 13)  // chain C: rows 13-16, joints 9-12
#undef FINGER

  // ---- chain D (little finger w/ metacarpal): Rodrigues about
  // w=(0.571,0,0.821), then Ry, then 3x Rx. Rows 17-20, joints 13-17. ----
  {
    const float a13 = clampf(al[13], 0.0f, 0.785f);
    const float wx = 0.571f, wz = 0.821f;
    const float s13 = __sinf(a13), c13 = __cosf(a13);
    const float t13 = 1.0f - c13;
    const float g00 = 1.0f - t13 * (wz * wz), g10 = s13 * wz, g20 = t13 * (wx * wz);
    const float g01 = -s13 * wz, g11 = 1.0f - t13 * (wx * wx + wz * wz), g21 = s13 * wx;
    const float g02 = t13 * (wx * wz), g12 = -s13 * wx, g22 = 1.0f - t13 * (wx * wx);
    const float gdx = -0.017f * g00 + 0.044f * g02;
    const float gdy = -0.017f * g10 + 0.044f * g12;
    const float gdz = -0.017f * g20 + 0.044f * g22;
    const float t17x = -0.017f + gdx;
    const float t17y = -0.044f * s0 + (c0 * gdy - s0 * gdz);
    const float t17z = 0.044f * c0 + (s0 * gdy + c0 * gdz);
    o[51] = t17x; o[52] = t17y; o[53] = t17z;  // row 17
    const float a14 = clampf(al[14], -0.349f, 0.349f);
    const float s14 = __sinf(a14), c14 = __cosf(a14);
    const float ux = g01, uy = c0 * g11 - s0 * g21, uz = s0 * g11 + c0 * g21;
    const float mx = s14 * g00 + c14 * g02;
    const float my = s14 * g10 + c14 * g12;
    const float mz = s14 * g20 + c14 * g22;
    const float vx = mx, vy = c0 * my - s0 * mz, vz = s0 * my + c0 * mz;
    const float g1 = clampf(al[15], 0.0f, 1.571f);
    const float g2 = g1 + clampf(al[16], 0.0f, 1.571f);
    const float g3 = g2 + clampf(al[17], 0.0f, 1.571f);
    const float s1 = __sinf(g1), c1 = __cosf(g1);
    const float s2 = __sinf(g2), c2 = __cosf(g2);
    const float s3 = __sinf(g3), c3 = __cosf(g3);
    const float q3y = -0.045f * s1, q3z = 0.045f * c1;
    const float q4y = q3y - 0.025f * s2, q4z = q3z + 0.025f * c2;
    const float q5y = q4y - 0.026f * s3, q5z = q4z + 0.026f * c3;
    o[54] = t17x + q3y * ux + q3z * vx;  // row 18
    o[55] = t17y + q3y * uy + q3z * vy;
    o[56] = t17z + q3y * uz + q3z * vz;
    o[57] = t17x + q4y * ux + q4z * vx;  // row 19
    o[58] = t17y + q4y * uy + q4z * vy;
    o[59] = t17z + q4y * uz + q4z * vz;
    o[60] = t17x + q5y * ux + q5z * vx;  // row 20
    o[61] = t17y + q5y * uy + q5z * vy;
    o[62] = t17z + q5y * uz + q5z * vz;
  }

  // ---- chain E (thumb): Rz(-a18), Rx(a19), Rx(a20), Ry(a21), Ry(a22).
  // Rows 1-4, joints 18-22. ----
  {
    const float a18 = clampf(al[18], -1.047f, 1.047f);
    const float s18 = __sinf(a18), c18 = __cosf(a18);
    const float t22x = 0.034f;
    const float t22y = -0.009f * c0 - 0.029f * s0;
    const float t22z = -0.009f * s0 + 0.029f * c0;
    o[3] = t22x; o[4] = t22y; o[5] = t22z;  // row 1 (node 22)
    const float a19 = clampf(al[19], 0.0f, 1.222f);
    const float a20 = clampf(al[20], -0.209f, 0.209f);
    const float a21 = clampf(al[21], -0.524f, 0.524f);
    const float a22 = clampf(al[22], -1.571f, 0.0f);
    const float s19 = __sinf(a19), c19 = __cosf(a19);
    const float sg = a19 + a20;
    const float ss = __sinf(sg), cs = __cosf(sg);
    const float s21 = __sinf(a21), c21 = __cosf(a21);
    const float ta = a21 + a22;
    const float st = __sinf(ta), ct = __cosf(ta);
    const float qAy = -0.038f * s19, qAz = 0.038f * c19;               // node 25
    const float q6x = 0.032f * s21;
    const float q6y = qAy - 0.032f * c21 * ss;
    const float q6z = qAz + 0.032f * c21 * cs;                         // node 26
    const float q7x = q6x + 0.0275f * st;
    const float q7y = q6y - 0.0275f * ct * ss;
    const float q7z = q6z + 0.0275f * ct * cs;                         // node 27
    const float m10 = c0 * s18, m11 = c0 * c18, m20 = s0 * s18, m21 = s0 * c18;
    o[6] = t22x + qAy * s18;                    // row 2 (node 25)
    o[7] = t22y + qAy * m11 - qAz * s0;
    o[8] = t22z + qAy * m21 + qAz * c0;
    o[9] = t22x + q6x * c18 + q6y * s18;        // row 3 (node 26)
    o[10] = t22y - q6x * m10 + q6y * m11 - q6z * s0;
    o[11] = t22z - q6x * m20 + q6y * m21 + q6z * c0;
    o[12] = t22x + q7x * c18 + q7y * s18;       // row 4 (node 27)
    o[13] = t22y - q7x * m10 + q7y * m11 - q7z * s0;
    o[14] = t22z - q7x * m20 + q7y * m21 + q7z * c0;
  }

  __syncthreads();  // all angle reads done; LDS free for output staging

  // ---- two-phase output staging: 32 elements' full 63-float rows at a
  // time -> contiguous float4 global stores. ----
#pragma unroll
  for (int p = 0; p < 2; ++p) {
    if ((tid >> 5) == p) {
      float* dst = lds + (tid & 31) * 63;  // stride 63: banks distinct mod 32
#pragma unroll
      for (int k = 0; k < 63; ++k) dst[k] = o[k];
    }
    __syncthreads();
    const float4* lsrc = reinterpret_cast<const float4*>(lds);
    float4* gdst = reinterpret_cast<float4*>(out + (base + 32 * p) * 63);
#pragma unroll
    for (int it = 0; it < 8; ++it) {
      int idx = tid + it * TPB;
      if (idx < (32 * 63) / 4) gdst[idx] = lsrc[idx];
    }
    __syncthreads();  // phase-0 reads done before phase-1 overwrites
  }
}

}  // namespace

extern "C" void kernel_launch(void* const* d_in, const int* in_sizes, int n_in,
                              void* d_out, int out_size, void* d_ws, size_t ws_size,
                              hipStream_t stream) {
  const float* angles = (const float*)d_in[0];
  float* out = (float*)d_out;
  const int Bn = in_sizes[0] / 23;   // 524288
  const int nblocks = Bn / TPB;      // 8192
  fk_kernel<<<nblocks, TPB, 0, stream>>>(angles, out);
}

// Round 4
// 33.019 us; speedup vs baseline: 1.2982x; 1.0042x over previous
//
#include <hip/hip_runtime.h>

namespace {

constexpr int TPB = 256;  // 4 waves; each wave computes one part of all 64 elements
constexpr int EPB = 64;   // elements per block

__device__ __forceinline__ float clampf(float x, float lo, float hi) {
  return fminf(fmaxf(x, lo), hi);
}

// All constants (axes, joint limits, translations) are static in the
// reference module and hard-coded/folded. 5 chains hang off node 0 (X-axis
// root rotation); consecutive X-rotations compose as cumulative angle sums.
//
// Wave-specialized: wave 0 = root + finger A, wave 1 = fingers B + C,
// wave 2 = little finger (metacarpal chain), wave 3 = thumb. Cuts per-thread
// registers ~2x (o[<=24] vs o[63]) -> 8 waves/SIMD; LDS 16128 B -> 8
// blocks/CU = 32 waves/CU.

__global__ __launch_bounds__(TPB, 8) void fk_kernel(
    const float* __restrict__ angles,
    float* __restrict__ out) {
  // 16128 B: angles staged in first 5888 B (64 x 23 f32), then the whole
  // buffer becomes 64 rows x 63 f32 of output staging.
  __shared__ float lds[EPB * 63];

  const int tid = threadIdx.x;
  const int lane = tid & 63;
  const int w = tid >> 6;  // wave id 0..3 (wave-uniform)
  const long long base = (long long)blockIdx.x * EPB;

  // ---- coalesced stage of this block's angles (368 float4, 256 threads) ----
  {
    const float4* __restrict__ src = reinterpret_cast<const float4*>(angles + base * 23);
    float4* dst = reinterpret_cast<float4*>(lds);
    dst[tid] = src[tid];                                   // 0..255
    if (tid + TPB < (EPB * 23) / 4) dst[tid + TPB] = src[tid + TPB];  // 256..367
  }
  __syncthreads();

  const float* al = lds + lane * 23;  // this wave's element = lane
  float o[24];                        // literal-indexed only

  const float a0 = clampf(al[0], -0.689f, 0.489f);
  const float s0 = __sinf(a0);
  const float c0 = __cosf(a0);

// ---- finger macro: t=(TX,0,TZ), Ry(knuckle al[J]), then 3x Rx with
// z-links 0.045/0.025/0.026. Writes o[OB..OB+11] (4 rows). ----
#define FINGER(TX, TZ, J, OB)                                                   \
  {                                                                             \
    const float aY = clampf(al[(J)], -0.349f, 0.349f);                          \
    const float sY = __sinf(aY), cY = __cosf(aY);                               \
    const float g1 = clampf(al[(J) + 1], 0.0f, 1.571f);                         \
    const float g2 = g1 + clampf(al[(J) + 2], 0.0f, 1.571f);                    \
    const float g3 = g2 + clampf(al[(J) + 3], 0.0f, 1.571f);                    \
    const float s1 = __sinf(g1), c1 = __cosf(g1);                               \
    const float s2 = __sinf(g2), c2 = __cosf(g2);                               \
    const float s3 = __sinf(g3), c3 = __cosf(g3);                               \
    const float t1x = (TX), t1y = -s0 * (TZ), t1z = c0 * (TZ);                  \
    const float vx = sY, vy = -s0 * cY, vz = c0 * cY; /* frame col2 */          \
    /* frame col1 = (0, c0, s0) */                                              \
    const float q3y = -0.045f * s1, q3z = 0.045f * c1;                          \
    const float q4y = q3y - 0.025f * s2, q4z = q3z + 0.025f * c2;               \
    const float q5y = q4y - 0.026f * s3, q5z = q4z + 0.026f * c3;               \
    o[(OB) + 0] = t1x; o[(OB) + 1] = t1y; o[(OB) + 2] = t1z;                    \
    o[(OB) + 3] = t1x + q3z * vx;                                               \
    o[(OB) + 4] = t1y + q3y * c0 + q3z * vy;                                    \
    o[(OB) + 5] = t1z + q3y * s0 + q3z * vz;                                    \
    o[(OB) + 6] = t1x + q4z * vx;                                               \
    o[(OB) + 7] = t1y + q4y * c0 + q4z * vy;                                    \
    o[(OB) + 8] = t1z + q4y * s0 + q4z * vz;                                    \
    o[(OB) + 9] = t1x + q5z * vx;                                               \
    o[(OB) + 10] = t1y + q5y * c0 + q5z * vy;                                   \
    o[(OB) + 11] = t1z + q5y * s0 + q5z * vz;                                   \
  }

  if (w == 0) {
    // root (row 0) + finger A (rows 5-8)
    o[0] = 0.0f; o[1] = 0.0f; o[2] = 0.0f;
    FINGER(0.033f, 0.095f, 1, 3)
  } else if (w == 1) {
    // finger B (rows 9-12) + finger C (rows 13-16)
    FINGER(0.011f, 0.099f, 5, 0)
    FINGER(-0.011f, 0.095f, 9, 12)
  } else if (w == 2) {
    // little finger w/ metacarpal: Rodrigues about w=(0.571,0,0.821),
    // then Ry, then 3x Rx. Rows 17-20 -> o[0..11].
    const float a13 = clampf(al[13], 0.0f, 0.785f);
    const float wx = 0.571f, wz = 0.821f;
    const float s13 = __sinf(a13), c13 = __cosf(a13);
    const float t13 = 1.0f - c13;
    const float g00 = 1.0f - t13 * (wz * wz), g10 = s13 * wz, g20 = t13 * (wx * wz);
    const float g01 = -s13 * wz, g11 = 1.0f - t13 * (wx * wx + wz * wz), g21 = s13 * wx;
    const float g02 = t13 * (wx * wz), g12 = -s13 * wx, g22 = 1.0f - t13 * (wx * wx);
    const float gdx = -0.017f * g00 + 0.044f * g02;
    const float gdy = -0.017f * g10 + 0.044f * g12;
    const float gdz = -0.017f * g20 + 0.044f * g22;
    const float t17x = -0.017f + gdx;
    const float t17y = -0.044f * s0 + (c0 * gdy - s0 * gdz);
    const float t17z = 0.044f * c0 + (s0 * gdy + c0 * gdz);
    o[0] = t17x; o[1] = t17y; o[2] = t17z;  // row 17
    const float a14 = clampf(al[14], -0.349f, 0.349f);
    const float s14 = __sinf(a14), c14 = __cosf(a14);
    const float ux = g01, uy = c0 * g11 - s0 * g21, uz = s0 * g11 + c0 * g21;
    const float mx = s14 * g00 + c14 * g02;
    const float my = s14 * g10 + c14 * g12;
    const float mz = s14 * g20 + c14 * g22;
    const float vx = mx, vy = c0 * my - s0 * mz, vz = s0 * my + c0 * mz;
    const float g1 = clampf(al[15], 0.0f, 1.571f);
    const float g2 = g1 + clampf(al[16], 0.0f, 1.571f);
    const float g3 = g2 + clampf(al[17], 0.0f, 1.571f);
    const float s1 = __sinf(g1), c1 = __cosf(g1);
    const float s2 = __sinf(g2), c2 = __cosf(g2);
    const float s3 = __sinf(g3), c3 = __cosf(g3);
    const float q3y = -0.045f * s1, q3z = 0.045f * c1;
    const float q4y = q3y - 0.025f * s2, q4z = q3z + 0.025f * c2;
    const float q5y = q4y - 0.026f * s3, q5z = q4z + 0.026f * c3;
    o[3] = t17x + q3y * ux + q3z * vx;  // row 18
    o[4] = t17y + q3y * uy + q3z * vy;
    o[5] = t17z + q3y * uz + q3z * vz;
    o[6] = t17x + q4y * ux + q4z * vx;  // row 19
    o[7] = t17y + q4y * uy + q4z * vy;
    o[8] = t17z + q4y * uz + q4z * vz;
    o[9] = t17x + q5y * ux + q5z * vx;  // row 20
    o[10] = t17y + q5y * uy + q5z * vy;
    o[11] = t17z + q5y * uz + q5z * vz;
  } else {
    // thumb: Rz(-a18), Rx(a19), Rx(a20), Ry(a21), Ry(a22). Rows 1-4 -> o[0..11].
    const float a18 = clampf(al[18], -1.047f, 1.047f);
    const float s18 = __sinf(a18), c18 = __cosf(a18);
    const float t22x = 0.034f;
    const float t22y = -0.009f * c0 - 0.029f * s0;
    const float t22z = -0.009f * s0 + 0.029f * c0;
    o[0] = t22x; o[1] = t22y; o[2] = t22z;  // row 1 (node 22)
    const float a19 = clampf(al[19], 0.0f, 1.222f);
    const float a20 = clampf(al[20], -0.209f, 0.209f);
    const float a21 = clampf(al[21], -0.524f, 0.524f);
    const float a22 = clampf(al[22], -1.571f, 0.0f);
    const float s19 = __sinf(a19), c19 = __cosf(a19);
    const float sg = a19 + a20;
    const float ss = __sinf(sg), cs = __cosf(sg);
    const float s21 = __sinf(a21), c21 = __cosf(a21);
    const float ta = a21 + a22;
    const float st = __sinf(ta), ct = __cosf(ta);
    const float qAy = -0.038f * s19, qAz = 0.038f * c19;  // node 25
    const float q6x = 0.032f * s21;
    const float q6y = qAy - 0.032f * c21 * ss;
    const float q6z = qAz + 0.032f * c21 * cs;            // node 26
    const float q7x = q6x + 0.0275f * st;
    const float q7y = q6y - 0.0275f * ct * ss;
    const float q7z = q6z + 0.0275f * ct * cs;            // node 27
    const float m10 = c0 * s18, m11 = c0 * c18, m20 = s0 * s18, m21 = s0 * c18;
    o[3] = t22x + qAy * s18;                  // row 2 (node 25)
    o[4] = t22y + qAy * m11 - qAz * s0;
    o[5] = t22z + qAy * m21 + qAz * c0;
    o[6] = t22x + q6x * c18 + q6y * s18;      // row 3 (node 26)
    o[7] = t22y - q6x * m10 + q6y * m11 - q6z * s0;
    o[8] = t22z - q6x * m20 + q6y * m21 + q6z * c0;
    o[9] = t22x + q7x * c18 + q7y * s18;      // row 4 (node 27)
    o[10] = t22y - q7x * m10 + q7y * m11 - q7z * s0;
    o[11] = t22z - q7x * m20 + q7y * m21 + q7z * c0;
  }
#undef FINGER

  __syncthreads();  // all angle reads complete before output overwrites

  // ---- write this wave's floats into the element's 63-float LDS row.
  // Addresses (lane*63 + c): distinct banks across 32 lanes, 2-way alias
  // across 64 = free. ----
  {
    float* row = lds + lane * 63;
    if (w == 0) {
      row[0] = o[0]; row[1] = o[1]; row[2] = o[2];
#pragma unroll
      for (int k = 0; k < 12; ++k) row[15 + k] = o[3 + k];
    } else if (w == 1) {
#pragma unroll
      for (int k = 0; k < 24; ++k) row[27 + k] = o[k];
    } else if (w == 2) {
#pragma unroll
      for (int k = 0; k < 12; ++k) row[51 + k] = o[k];
    } else {
#pragma unroll
      for (int k = 0; k < 12; ++k) row[3 + k] = o[k];
    }
  }
  __syncthreads();

  // ---- coalesced block store: 1008 float4 over 256 threads ----
  {
    const float4* lsrc = reinterpret_cast<const float4*>(lds);
    float4* gdst = reinterpret_cast<float4*>(out + base * 63);
#pragma unroll
    for (int k = 0; k < 4; ++k) {
      int idx = tid + k * TPB;
      if (idx < (EPB * 63) / 4) gdst[idx] = lsrc[idx];
    }
  }
}

}  // namespace

extern "C" void kernel_launch(void* const* d_in, const int* in_sizes, int n_in,
                              void* d_out, int out_size, void* d_ws, size_t ws_size,
                              hipStream_t stream) {
  const float* angles = (const float*)d_in[0];
  float* out = (float*)d_out;
  const int Bn = in_sizes[0] / 23;   // 524288
  const int nblocks = Bn / EPB;      // 8192
  fk_kernel<<<nblocks, TPB, 0, stream>>>(angles, out);
}